// Round 12
// baseline (1041.188 us; speedup 1.0000x reference)
//
#include <hip/hip_runtime.h>
#include <hip/hip_bf16.h>
#include <math.h>

#define NNODES 50000
#define NEDGES 500000
#define NLAYERS 8
#define NSCANB 196  // ceil(NNODES/256)
#define CSRMAX (NEDGES + 3 * NNODES)  // padded-to-4 worst case
#define LROW 272  // LDS agg row stride bytes (17*16: b128-aligned, 2-way banks)

typedef __attribute__((ext_vector_type(8))) short bhalf8;
typedef __attribute__((ext_vector_type(4))) float f32x4;

// K-dim permutation: packed pos p <-> natural dim d = 16*(p&7) + (p>>3).
static __device__ __forceinline__ int invp(int p) { return 16 * (p & 7) + (p >> 3); }

static __device__ __forceinline__ unsigned short f2b(float v) {
    unsigned u = __builtin_bit_cast(unsigned, v);
    u += 0x7fffu + ((u >> 16) & 1u);
    return (unsigned short)(u >> 16);
}
static __device__ __forceinline__ float b2f(unsigned short w) {
    return __builtin_bit_cast(float, (unsigned)w << 16);
}
static __device__ __forceinline__ float b2f_lo(unsigned w) {
    return __builtin_bit_cast(float, w << 16);
}
static __device__ __forceinline__ float b2f_hi(unsigned w) {
    return __builtin_bit_cast(float, w & 0xffff0000u);
}
static __device__ __forceinline__ float ub(unsigned a, int k) {
    return (float)((a >> (8 * k)) & 0xffu);  // folds to v_cvt_f32_ubyteN
}

// ---------------- graph preprocessing ----------------

__global__ void k_count(const int* __restrict__ col, int* __restrict__ counts) {
    int e = blockIdx.x * 256 + threadIdx.x;
    if (e < NEDGES) atomicAdd(&counts[col[e]], 1);
}

__global__ __launch_bounds__(256) void k_dinv_bsum(const int* __restrict__ counts,
                                                   float* __restrict__ dinv,
                                                   int* __restrict__ part) {
    __shared__ int ls[256];
    int t = threadIdx.x, i = blockIdx.x * 256 + t;
    int cnt = (i < NNODES) ? counts[i] : 0;
    if (i < NNODES) dinv[i] = rsqrtf((float)(cnt + 1));
    ls[t] = (i < NNODES) ? ((cnt + 3) & ~3) : 0;
    __syncthreads();
    for (int o = 128; o > 0; o >>= 1) {
        if (t < o) ls[t] += ls[t + o];
        __syncthreads();
    }
    if (t == 0) part[blockIdx.x] = ls[0];
}

__global__ __launch_bounds__(256) void k_pscan(int* __restrict__ part) {
    __shared__ int ls[256];
    int t = threadIdx.x;
    int v = (t < NSCANB) ? part[t] : 0;
    ls[t] = v;
    __syncthreads();
    for (int o = 1; o < 256; o <<= 1) {
        int x = (t >= o) ? ls[t - o] : 0;
        __syncthreads();
        ls[t] += x;
        __syncthreads();
    }
    if (t < NSCANB) part[t] = ls[t] - v;
}

__global__ __launch_bounds__(256) void k_offs(const int* __restrict__ counts,
                                              const int* __restrict__ part,
                                              int* __restrict__ offs) {
    __shared__ int ls[256];
    int t = threadIdx.x, i = blockIdx.x * 256 + t;
    int v = (i < NNODES) ? ((counts[i] + 3) & ~3) : 0;
    ls[t] = v;
    __syncthreads();
    for (int o = 1; o < 256; o <<= 1) {
        int x = (t >= o) ? ls[t - o] : 0;
        __syncthreads();
        ls[t] += x;
        __syncthreads();
    }
    int excl = part[blockIdx.x] + ls[t] - v;
    if (i < NNODES) offs[i] = excl;
    if (i == NNODES - 1) offs[NNODES] = excl + v;
}

// csr pre-memset to 0 -> pad entries are {row 0, w 0.0f}
__global__ void k_scatter(const int* __restrict__ row, const int* __restrict__ col,
                          const int* __restrict__ offs, int* __restrict__ cursor,
                          const float* __restrict__ dinv, int2* __restrict__ csr) {
    int e = blockIdx.x * 256 + threadIdx.x;
    if (e < NEDGES) {
        int c = col[e], r = row[e];
        int pos = offs[c] + atomicAdd(&cursor[c], 1);
        float w = dinv[r] * dinv[c];
        csr[pos] = make_int2(r, __builtin_bit_cast(int, w));
    }
}

// ---------------- folded + packed layer weights (K-permuted) ----------------
__global__ void k_wcp2(const float* __restrict__ w1, const float* __restrict__ w2,
                       unsigned short* __restrict__ Wp) {
    int idx = blockIdx.x * 256 + threadIdx.x;
    if (idx >= NLAYERS * 32768) return;
    int i = idx >> 15;
    int rem = idx & 32767;
    int s = rem >> 12;
    int t = (rem >> 9) & 7;
    int lane = (rem >> 3) & 63;
    int j = rem & 7;
    int kf = s * 32 + (lane >> 4) * 8 + j;
    int n = t * 16 + (lane & 15);
    float beta = logf(1.0f / (float)(i + 1) + 1.0f);
    float v;
    if (kf < 128) {
        int k = invp(kf);
        v = beta * w1[(i * 128 + k) * 128 + n] + ((k == n) ? (1.0f - beta) : 0.0f);
    } else {
        int k2 = invp(kf - 128);
        v = 0.5f * (beta * w2[(i * 128 + k2) * 128 + n] + ((k2 == n) ? (1.0f - beta) : 0.0f));
    }
    Wp[idx] = f2b(v);
}

// ---------------- lin1 (MFMA): h0 -> h0p (128-dim bf16 packed rows) ----------------
__global__ __launch_bounds__(256) void k_lin1m(const float* __restrict__ x,
                                               const float* __restrict__ W,
                                               const float* __restrict__ b,
                                               unsigned short* __restrict__ h0p) {
    __shared__ __attribute__((aligned(16))) unsigned short Bs[8192];
    int t = threadIdx.x;
    for (int idx = t; idx < 8192; idx += 256) {
        int s = idx >> 12;
        int tt = (idx >> 9) & 7;
        int lane = (idx >> 3) & 63;
        int j = idx & 7;
        int k = s * 32 + (lane >> 4) * 8 + j;
        int n = tt * 16 + (lane & 15);
        Bs[idx] = f2b(W[k * 128 + n]);
    }
    __syncthreads();

    int w = t >> 6, lane = t & 63;
    int q = lane >> 4, r = lane & 15;
    int m0 = blockIdx.x * 64 + w * 16;
    int mA = m0 + r; if (mA > NNODES - 1) mA = NNODES - 1;
    const float* xrow = x + (size_t)mA * 64;

    f32x4 acc[8];
#pragma unroll
    for (int tt = 0; tt < 8; ++tt) {
        float bv = b[tt * 16 + r];
        acc[tt] = (f32x4){bv, bv, bv, bv};
    }
#pragma unroll
    for (int s = 0; s < 2; ++s) {
        float xv[8];
        *(float4*)&xv[0] = *(const float4*)(xrow + s * 32 + q * 8);
        *(float4*)&xv[4] = *(const float4*)(xrow + s * 32 + q * 8 + 4);
        bhalf8 ah, al;
#pragma unroll
        for (int j = 0; j < 8; ++j) {
            unsigned short hb = f2b(xv[j]);
            ah[j] = (short)hb;
            al[j] = (short)f2b(xv[j] - b2f(hb));
        }
#pragma unroll
        for (int tt = 0; tt < 8; ++tt) {
            bhalf8 bf = *(const bhalf8*)&Bs[((s * 8 + tt) << 9) + lane * 8];
            acc[tt] = __builtin_amdgcn_mfma_f32_16x16x32_bf16(ah, bf, acc[tt], 0, 0, 0);
            acc[tt] = __builtin_amdgcn_mfma_f32_16x16x32_bf16(al, bf, acc[tt], 0, 0, 0);
        }
    }
#pragma unroll
    for (int i = 0; i < 4; ++i) {
        int mm = m0 + q * 4 + i;
        if (mm < NNODES) {
            bhalf8 hv;
#pragma unroll
            for (int tt = 0; tt < 8; ++tt) hv[tt] = (short)f2b(acc[tt][i]);
            *(bhalf8*)&h0p[(size_t)mm * 128 + 8 * r] = hv;
        }
    }
}

// ---------------- fused layer: SpMM(tile rows -> LDS) + MFMA GEMM + stats ----------------
// grid 391 x 256. U8=1: gather hact(u8,128B rows)+qs; U8=0 (layer 0): gather h0p (bf16, 256B rows).
template <int U8>
__global__ __launch_bounds__(256) void k_layer(const unsigned char* __restrict__ srcu,
                                               const float* __restrict__ qs,
                                               const unsigned short* __restrict__ h0p,
                                               const int* __restrict__ offs,
                                               const int2* __restrict__ csr,
                                               const float* __restrict__ dinv,
                                               const unsigned short* __restrict__ Bp,
                                               unsigned short* __restrict__ outb,
                                               float* __restrict__ stats) {
    __shared__ __attribute__((aligned(16))) unsigned char lds[128 * LROW];  // 34 KB
    int t = threadIdx.x;
    int m0 = blockIdx.x * 128;
    unsigned s = t & 31;

    // ---- phase 1: agg rows of this tile -> LDS (bf16 packed, stride LROW) ----
#pragma unroll 1
    for (int pass = 0; pass < 16; ++pass) {
        int ln = pass * 8 + (t >> 5);
        int c = m0 + ln;
        uint2 outv = make_uint2(0, 0);
        if (c < NNODES) {
            float di = dinv[c];
            float dw = di * di;
            float acc0, acc1, acc2, acc3;
            if (U8) {
                unsigned a = *(const unsigned*)(srcu + (((unsigned)c << 7) + s * 4));
                float dws = dw * qs[c];
                acc0 = dws * ub(a, 0); acc1 = dws * ub(a, 1);
                acc2 = dws * ub(a, 2); acc3 = dws * ub(a, 3);
            } else {
                uint2 g = *(const uint2*)((const unsigned char*)h0p + (((unsigned)c << 8) + s * 8));
                acc0 = dw * b2f_lo(g.x); acc1 = dw * b2f_hi(g.x);
                acc2 = dw * b2f_lo(g.y); acc3 = dw * b2f_hi(g.y);
            }
            int e = offs[c], e1 = offs[c + 1];  // multiples of 4; pads w=0
            for (; e < e1; e += 4) {
                int2 E[4];
#pragma unroll
                for (int u = 0; u < 4; ++u) E[u] = csr[e + u];
                if (U8) {
                    unsigned a[4];
                    float wv[4];
#pragma unroll
                    for (int u = 0; u < 4; ++u) {
                        wv[u] = __builtin_bit_cast(float, E[u].y) * qs[E[u].x];
                        a[u] = *(const unsigned*)(srcu + (((unsigned)E[u].x << 7) + s * 4));
                    }
#pragma unroll
                    for (int u = 0; u < 4; ++u) {
                        acc0 = fmaf(wv[u], ub(a[u], 0), acc0);
                        acc1 = fmaf(wv[u], ub(a[u], 1), acc1);
                        acc2 = fmaf(wv[u], ub(a[u], 2), acc2);
                        acc3 = fmaf(wv[u], ub(a[u], 3), acc3);
                    }
                } else {
                    uint2 g[4];
#pragma unroll
                    for (int u = 0; u < 4; ++u)
                        g[u] = *(const uint2*)((const unsigned char*)h0p +
                                               (((unsigned)E[u].x << 8) + s * 8));
#pragma unroll
                    for (int u = 0; u < 4; ++u) {
                        float wv = __builtin_bit_cast(float, E[u].y);
                        acc0 = fmaf(wv, b2f_lo(g[u].x), acc0);
                        acc1 = fmaf(wv, b2f_hi(g[u].x), acc1);
                        acc2 = fmaf(wv, b2f_lo(g[u].y), acc2);
                        acc3 = fmaf(wv, b2f_hi(g[u].y), acc3);
                    }
                }
            }
            outv.x = (unsigned)f2b(0.5f * acc0) | ((unsigned)f2b(0.5f * acc1) << 16);
            outv.y = (unsigned)f2b(0.5f * acc2) | ((unsigned)f2b(0.5f * acc3) << 16);
        }
        *(uint2*)&lds[ln * LROW + s * 8] = outv;
    }
    __syncthreads();

    // ---- phase 2: [aggLDS | h0p] @ Wp(global) -> outb + stats ----
    int w = t >> 6, lane = t & 63;
    int q = lane >> 4, r = lane & 15;
    float ps1 = 0.f, ps2 = 0.f;

#pragma unroll 1
    for (int sub = 0; sub < 2; ++sub) {
        int lr = sub * 64 + w * 16 + r;
        int mA = m0 + lr; if (mA > NNODES - 1) mA = NNODES - 1;
        const unsigned short* h0row = h0p + (size_t)mA * 128;

        f32x4 acc[8];
#pragma unroll
        for (int i = 0; i < 8; ++i) acc[i] = (f32x4){0.f, 0.f, 0.f, 0.f};

        bhalf8 afr[8];
#pragma unroll
        for (int ss = 0; ss < 4; ++ss)
            afr[ss] = *(const bhalf8*)&lds[lr * LROW + ss * 64 + q * 16];
#pragma unroll
        for (int ss = 4; ss < 8; ++ss)
            afr[ss] = *(const bhalf8*)(h0row + (ss - 4) * 32 + q * 8);
#pragma unroll
        for (int ss = 0; ss < 8; ++ss) {
#pragma unroll
            for (int nt = 0; nt < 8; ++nt) {
                bhalf8 bfr = *(const bhalf8*)&Bp[((ss * 8 + nt) << 9) + lane * 8];
                acc[nt] = __builtin_amdgcn_mfma_f32_16x16x32_bf16(afr[ss], bfr, acc[nt], 0, 0, 0);
            }
        }
#pragma unroll
        for (int i = 0; i < 4; ++i) {
            int mm = m0 + sub * 64 + w * 16 + q * 4 + i;
            if (mm < NNODES) {
                bhalf8 hv;
#pragma unroll
                for (int nt = 0; nt < 8; ++nt) {
                    float v = acc[nt][i];
                    ps1 += v; ps2 += v * v;
                    hv[nt] = (short)f2b(v);
                }
                *(bhalf8*)&outb[(size_t)mm * 128 + 8 * r] = hv;
            }
        }
    }
    __syncthreads();
    float* red = (float*)lds;
    red[t] = ps1; red[256 + t] = ps2;
    __syncthreads();
    for (int o = 128; o > 0; o >>= 1) {
        if (t < o) { red[t] += red[t + o]; red[256 + t] += red[256 + t + o]; }
        __syncthreads();
    }
    if (t == 0) {
        atomicAdd(stats, red[0]);
        atomicAdd(stats + 1, red[256]);
    }
}

// ---------------- activation: per-row u8 quant of relu(LN(outb)), exact rowmax scale ----------------
__global__ __launch_bounds__(256) void k_actq(const unsigned short* __restrict__ outb,
                                              const float* __restrict__ stats,
                                              const float* __restrict__ nw,
                                              const float* __restrict__ nb,
                                              unsigned char* __restrict__ hact,
                                              float* __restrict__ qs) {
    __shared__ float skp[128], ckp[128];
    int t = threadIdx.x;
    const float M = (float)NNODES * 128.0f;
    float mean = stats[0] / M;
    float var = stats[1] / M - mean * mean;
    float inv = 1.0f / (sqrtf(fmaxf(var, 0.0f)) + 1e-5f);
    if (t < 128) {
        int d = invp(t);
        float sk = inv * nw[d];
        skp[t] = sk;
        ckp[t] = nb[d] - mean * sk;
    }
    __syncthreads();
    int row = blockIdx.x * 8 + (t >> 5);
    int s = t & 31;
    if (row >= NNODES) return;
    uint2 g = *(const uint2*)(outb + (size_t)row * 128 + s * 4);
    float h[4];
    h[0] = fmaxf(fmaf(b2f_lo(g.x), skp[4 * s + 0], ckp[4 * s + 0]), 0.0f);
    h[1] = fmaxf(fmaf(b2f_hi(g.x), skp[4 * s + 1], ckp[4 * s + 1]), 0.0f);
    h[2] = fmaxf(fmaf(b2f_lo(g.y), skp[4 * s + 2], ckp[4 * s + 2]), 0.0f);
    h[3] = fmaxf(fmaf(b2f_hi(g.y), skp[4 * s + 3], ckp[4 * s + 3]), 0.0f);
    float rmax = fmaxf(fmaxf(h[0], h[1]), fmaxf(h[2], h[3]));
#pragma unroll
    for (int o = 1; o < 32; o <<= 1) rmax = fmaxf(rmax, __shfl_xor(rmax, o));
    float rs = (rmax > 0.f) ? 255.0f / rmax : 0.0f;
    unsigned pk = 0;
#pragma unroll
    for (int k = 0; k < 4; ++k) {
        float a = fminf(h[k] * rs, 255.0f);
        pk |= __float2uint_rn(a) << (8 * k);
    }
    *(unsigned*)(hact + (size_t)row * 128 + s * 4) = pk;
    if (s == 0) qs[row] = (rmax > 0.f) ? rmax * (1.0f / 255.0f) : 0.0f;
}

// ---------------- lin2 (MFMA) with fused final LayerNorm+ReLU ----------------
__global__ __launch_bounds__(256) void k_lin2m(const unsigned short* __restrict__ outb,
                                               const float* __restrict__ stats,
                                               const float* __restrict__ nw,
                                               const float* __restrict__ nb,
                                               const float* __restrict__ W,
                                               const float* __restrict__ b,
                                               float* __restrict__ out) {
    __shared__ __attribute__((aligned(16))) unsigned short Bs[8192];
    __shared__ float lskp[128], lckp[128];
    int t = threadIdx.x;
    const float M = (float)NNODES * 128.0f;
    float mean = stats[0] / M;
    float var = stats[1] / M - mean * mean;
    float inv = 1.0f / (sqrtf(fmaxf(var, 0.0f)) + 1e-5f);
    for (int idx = t; idx < 8192; idx += 256) {
        int s = idx >> 11;
        int tt = (idx >> 9) & 3;
        int lane = (idx >> 3) & 63;
        int j = idx & 7;
        int kf = s * 32 + (lane >> 4) * 8 + j;
        int k = invp(kf);
        int n = tt * 16 + (lane & 15);
        Bs[idx] = f2b(W[k * 64 + n]);
    }
    if (t < 128) {
        int d = invp(t);
        float sk = inv * nw[d];
        lskp[t] = sk;
        lckp[t] = nb[d] - mean * sk;
    }
    __syncthreads();

    int w = t >> 6, lane = t & 63;
    int q = lane >> 4, r = lane & 15;
    int m0 = blockIdx.x * 64 + w * 16;
    int mA = m0 + r; if (mA > NNODES - 1) mA = NNODES - 1;
    const unsigned short* arow = outb + (size_t)mA * 128;

    f32x4 acc[4];
#pragma unroll
    for (int tt = 0; tt < 4; ++tt) {
        float bv = b[tt * 16 + r];
        acc[tt] = (f32x4){bv, bv, bv, bv};
    }
#pragma unroll
    for (int s = 0; s < 4; ++s) {
        bhalf8 raw = *(const bhalf8*)(arow + s * 32 + q * 8);
        bhalf8 af;
#pragma unroll
        for (int j = 0; j < 8; ++j) {
            int p = s * 32 + q * 8 + j;
            float v = b2f((unsigned short)raw[j]);
            v = fmaxf(fmaf(v, lskp[p], lckp[p]), 0.0f);
            af[j] = (short)f2b(v);
        }
#pragma unroll
        for (int tt = 0; tt < 4; ++tt) {
            bhalf8 bf = *(const bhalf8*)&Bs[((s * 4 + tt) << 9) + lane * 8];
            acc[tt] = __builtin_amdgcn_mfma_f32_16x16x32_bf16(af, bf, acc[tt], 0, 0, 0);
        }
    }
#pragma unroll
    for (int i = 0; i < 4; ++i) {
        int mm = m0 + q * 4 + i;
        if (mm < NNODES) {
#pragma unroll
            for (int tt = 0; tt < 4; ++tt)
                out[(size_t)mm * 64 + tt * 16 + r] = acc[tt][i];
        }
    }
}

// ---------------- launch ----------------

extern "C" void kernel_launch(void* const* d_in, const int* in_sizes, int n_in,
                              void* d_out, int out_size, void* d_ws, size_t ws_size,
                              hipStream_t stream) {
    const float* x      = (const float*)d_in[0];
    const int*   ei     = (const int*)d_in[1];
    const float* lin1_w = (const float*)d_in[2];
    const float* lin1_b = (const float*)d_in[3];
    const float* w1     = (const float*)d_in[4];
    const float* w2     = (const float*)d_in[5];
    const float* norm_w = (const float*)d_in[6];
    const float* norm_b = (const float*)d_in[7];
    const float* lin2_w = (const float*)d_in[8];
    const float* lin2_b = (const float*)d_in[9];
    float* out = (float*)d_out;

    const int* row = ei;
    const int* col = ei + NEDGES;

    char* p = (char*)d_ws;
    auto take = [&](size_t bytes) -> char* {
        char* r = p;
        p += (bytes + 255) & ~(size_t)255;
        return r;
    };
    unsigned short* h0p  = (unsigned short*)take((size_t)NNODES * 128 * 2);  // h0 bf16 packed
    unsigned short* outb = (unsigned short*)take((size_t)NNODES * 128 * 2);  // layer out bf16 packed
    unsigned char*  hact = (unsigned char*)take((size_t)NNODES * 128);       // activated u8
    float*          qs   = (float*)take((size_t)NNODES * 4);                 // per-row dequant scale
    unsigned short* Wp   = (unsigned short*)take((size_t)NLAYERS * 32768 * 2);
    float* dinv    = (float*)take((size_t)NNODES * 4);
    // contiguous zero-init zone: counts | cursor | stats
    char* zzone    = take((size_t)NNODES * 4 * 2 + 256);
    int*   counts  = (int*)zzone;
    int*   cursor  = (int*)(zzone + (size_t)NNODES * 4);
    float* stats   = (float*)(zzone + (size_t)NNODES * 4 * 2);
    int*   offs    = (int*)take((size_t)(NNODES + 1) * 4);
    int*   part    = (int*)take((size_t)NSCANB * 4);
    int2*  csr     = (int2*)take((size_t)CSRMAX * 8);

    hipMemsetAsync(zzone, 0, (size_t)NNODES * 4 * 2 + 256, stream);
    hipMemsetAsync(csr, 0, (size_t)CSRMAX * 8, stream);  // pads = {row 0, w 0}

    k_count<<<(NEDGES + 255) / 256, 256, 0, stream>>>(col, counts);
    k_dinv_bsum<<<NSCANB, 256, 0, stream>>>(counts, dinv, part);
    k_pscan<<<1, 256, 0, stream>>>(part);
    k_offs<<<NSCANB, 256, 0, stream>>>(counts, part, offs);
    k_scatter<<<(NEDGES + 255) / 256, 256, 0, stream>>>(row, col, offs, cursor, dinv, csr);
    k_wcp2<<<(NLAYERS * 32768 + 255) / 256, 256, 0, stream>>>(w1, w2, Wp);
    k_lin1m<<<(NNODES + 63) / 64, 256, 0, stream>>>(x, lin1_w, lin1_b, h0p);

    const int NLB = (NNODES + 127) / 128;  // 391
    for (int i = 0; i < NLAYERS; ++i) {
        if (i == 0) {
            k_layer<0><<<NLB, 256, 0, stream>>>(nullptr, nullptr, h0p, offs, csr, dinv,
                                                Wp + (size_t)i * 32768, outb, stats + 2 * i);
        } else {
            k_layer<1><<<NLB, 256, 0, stream>>>(hact, qs, h0p, offs, csr, dinv,
                                                Wp + (size_t)i * 32768, outb, stats + 2 * i);
        }
        if (i < NLAYERS - 1) {
            k_actq<<<(NNODES + 7) / 8, 256, 0, stream>>>(outb, stats + 2 * i,
                                                         norm_w + (size_t)i * 128,
                                                         norm_b + (size_t)i * 128,
                                                         hact, qs);
        }
    }
    k_lin2m<<<(NNODES + 63) / 64, 256, 0, stream>>>(outb, stats + 14,
                                                    norm_w + 7 * 128, norm_b + 7 * 128,
                                                    lin2_w, lin2_b, out);
}

// Round 13
// 588.613 us; speedup vs baseline: 1.7689x; 1.7689x over previous
//
#include <hip/hip_runtime.h>
#include <hip/hip_bf16.h>
#include <math.h>

#define NNODES 50000
#define NEDGES 500000
#define NLAYERS 8
#define NSCANB 196  // ceil(NNODES/256)
#define CSRMAX (NEDGES + 3 * NNODES)  // padded-to-4 worst case

typedef __attribute__((ext_vector_type(8))) short bhalf8;
typedef __attribute__((ext_vector_type(4))) float f32x4;

// K-dim permutation: packed pos p <-> natural dim d = 16*(p&7) + (p>>3).
static __device__ __forceinline__ int invp(int p) { return 16 * (p & 7) + (p >> 3); }

static __device__ __forceinline__ unsigned short f2b(float v) {
    unsigned u = __builtin_bit_cast(unsigned, v);
    u += 0x7fffu + ((u >> 16) & 1u);
    return (unsigned short)(u >> 16);
}
static __device__ __forceinline__ float b2f(unsigned short w) {
    return __builtin_bit_cast(float, (unsigned)w << 16);
}
static __device__ __forceinline__ float b2f_lo(unsigned w) {
    return __builtin_bit_cast(float, w << 16);
}
static __device__ __forceinline__ float b2f_hi(unsigned w) {
    return __builtin_bit_cast(float, w & 0xffff0000u);
}
static __device__ __forceinline__ float ub(unsigned a, int k) {
    return (float)((a >> (8 * k)) & 0xffu);  // folds to v_cvt_f32_ubyteN
}

// ---------------- graph preprocessing ----------------

__global__ void k_count(const int* __restrict__ col, int* __restrict__ counts) {
    int e = blockIdx.x * 256 + threadIdx.x;
    if (e < NEDGES) atomicAdd(&counts[col[e]], 1);
}

__global__ __launch_bounds__(256) void k_dinv_bsum(const int* __restrict__ counts,
                                                   float* __restrict__ dinv,
                                                   int* __restrict__ part) {
    __shared__ int ls[256];
    int t = threadIdx.x, i = blockIdx.x * 256 + t;
    int cnt = (i < NNODES) ? counts[i] : 0;
    if (i < NNODES) dinv[i] = rsqrtf((float)(cnt + 1));
    ls[t] = (i < NNODES) ? ((cnt + 3) & ~3) : 0;
    __syncthreads();
    for (int o = 128; o > 0; o >>= 1) {
        if (t < o) ls[t] += ls[t + o];
        __syncthreads();
    }
    if (t == 0) part[blockIdx.x] = ls[0];
}

__global__ __launch_bounds__(256) void k_pscan(int* __restrict__ part) {
    __shared__ int ls[256];
    int t = threadIdx.x;
    int v = (t < NSCANB) ? part[t] : 0;
    ls[t] = v;
    __syncthreads();
    for (int o = 1; o < 256; o <<= 1) {
        int x = (t >= o) ? ls[t - o] : 0;
        __syncthreads();
        ls[t] += x;
        __syncthreads();
    }
    if (t < NSCANB) part[t] = ls[t] - v;
}

__global__ __launch_bounds__(256) void k_offs(const int* __restrict__ counts,
                                              const int* __restrict__ part,
                                              int* __restrict__ offs) {
    __shared__ int ls[256];
    int t = threadIdx.x, i = blockIdx.x * 256 + t;
    int v = (i < NNODES) ? ((counts[i] + 3) & ~3) : 0;
    ls[t] = v;
    __syncthreads();
    for (int o = 1; o < 256; o <<= 1) {
        int x = (t >= o) ? ls[t - o] : 0;
        __syncthreads();
        ls[t] += x;
        __syncthreads();
    }
    int excl = part[blockIdx.x] + ls[t] - v;
    if (i < NNODES) offs[i] = excl;
    if (i == NNODES - 1) offs[NNODES] = excl + v;
}

// csr pre-memset to 0 -> pad entries are {row 0, w 0.0f}
__global__ void k_scatter(const int* __restrict__ row, const int* __restrict__ col,
                          const int* __restrict__ offs, int* __restrict__ cursor,
                          const float* __restrict__ dinv, int2* __restrict__ csr) {
    int e = blockIdx.x * 256 + threadIdx.x;
    if (e < NEDGES) {
        int c = col[e], r = row[e];
        int pos = offs[c] + atomicAdd(&cursor[c], 1);
        float w = dinv[r] * dinv[c];
        csr[pos] = make_int2(r, __builtin_bit_cast(int, w));
    }
}

// ---------------- folded + packed layer weights (K-permuted) ----------------
__global__ void k_wcp2(const float* __restrict__ w1, const float* __restrict__ w2,
                       unsigned short* __restrict__ Wp) {
    int idx = blockIdx.x * 256 + threadIdx.x;
    if (idx >= NLAYERS * 32768) return;
    int i = idx >> 15;
    int rem = idx & 32767;
    int s = rem >> 12;
    int t = (rem >> 9) & 7;
    int lane = (rem >> 3) & 63;
    int j = rem & 7;
    int kf = s * 32 + (lane >> 4) * 8 + j;
    int n = t * 16 + (lane & 15);
    float beta = logf(1.0f / (float)(i + 1) + 1.0f);
    float v;
    if (kf < 128) {
        int k = invp(kf);
        v = beta * w1[(i * 128 + k) * 128 + n] + ((k == n) ? (1.0f - beta) : 0.0f);
    } else {
        int k2 = invp(kf - 128);
        v = 0.5f * (beta * w2[(i * 128 + k2) * 128 + n] + ((k2 == n) ? (1.0f - beta) : 0.0f));
    }
    Wp[idx] = f2b(v);
}

// ---------------- lin1 (MFMA): h0 -> abuf[:,128:256) bf16 packed ----------------
__global__ __launch_bounds__(256) void k_lin1m(const float* __restrict__ x,
                                               const float* __restrict__ W,
                                               const float* __restrict__ b,
                                               unsigned short* __restrict__ abuf) {
    __shared__ __attribute__((aligned(16))) unsigned short Bs[8192];
    int t = threadIdx.x;
    for (int idx = t; idx < 8192; idx += 256) {
        int s = idx >> 12;
        int tt = (idx >> 9) & 7;
        int lane = (idx >> 3) & 63;
        int j = idx & 7;
        int k = s * 32 + (lane >> 4) * 8 + j;
        int n = tt * 16 + (lane & 15);
        Bs[idx] = f2b(W[k * 128 + n]);
    }
    __syncthreads();

    int w = t >> 6, lane = t & 63;
    int q = lane >> 4, r = lane & 15;
    int m0 = blockIdx.x * 64 + w * 16;
    int mA = m0 + r; if (mA > NNODES - 1) mA = NNODES - 1;
    const float* xrow = x + (size_t)mA * 64;

    f32x4 acc[8];
#pragma unroll
    for (int tt = 0; tt < 8; ++tt) {
        float bv = b[tt * 16 + r];
        acc[tt] = (f32x4){bv, bv, bv, bv};
    }
#pragma unroll
    for (int s = 0; s < 2; ++s) {
        float xv[8];
        *(float4*)&xv[0] = *(const float4*)(xrow + s * 32 + q * 8);
        *(float4*)&xv[4] = *(const float4*)(xrow + s * 32 + q * 8 + 4);
        bhalf8 ah, al;
#pragma unroll
        for (int j = 0; j < 8; ++j) {
            unsigned short hb = f2b(xv[j]);
            ah[j] = (short)hb;
            al[j] = (short)f2b(xv[j] - b2f(hb));
        }
#pragma unroll
        for (int tt = 0; tt < 8; ++tt) {
            bhalf8 bf = *(const bhalf8*)&Bs[((s * 8 + tt) << 9) + lane * 8];
            acc[tt] = __builtin_amdgcn_mfma_f32_16x16x32_bf16(ah, bf, acc[tt], 0, 0, 0);
            acc[tt] = __builtin_amdgcn_mfma_f32_16x16x32_bf16(al, bf, acc[tt], 0, 0, 0);
        }
    }
#pragma unroll
    for (int i = 0; i < 4; ++i) {
        int mm = m0 + q * 4 + i;
        if (mm < NNODES) {
            bhalf8 hv;
#pragma unroll
            for (int tt = 0; tt < 8; ++tt) hv[tt] = (short)f2b(acc[tt][i]);
            *(bhalf8*)&abuf[(size_t)mm * 256 + 128 + 8 * r] = hv;
        }
    }
}

// ---------------- SpMM: padded CSR, 32-bit byte-offset gathers ----------------
// U8=1: gather hact (u8, 128 B rows) + qs; U8=0 (layer 0): gather h0 = abuf right
// half (bf16 packed, 512 B row stride).
template <int U8>
__global__ __launch_bounds__(256) void k_spmm9(const unsigned char* __restrict__ srcu,
                                               const float* __restrict__ qs,
                                               const unsigned char* __restrict__ srcb,
                                               const int* __restrict__ offs,
                                               const int2* __restrict__ csr,
                                               const float* __restrict__ dinv,
                                               unsigned short* __restrict__ abuf) {
    int gt = blockIdx.x * 256 + threadIdx.x;
    int c = gt >> 5;          // node (2 per wave)
    unsigned s = threadIdx.x & 31;  // packed dims [4s, 4s+4)
    if (c >= NNODES) return;
    unsigned s4 = s * 4, s8 = s * 8;
    float di = dinv[c];
    float dw = di * di;
    float acc0, acc1, acc2, acc3;
    if (U8) {
        unsigned a = *(const unsigned*)(srcu + (((unsigned)c << 7) + s4));
        float dws = dw * qs[c];
        acc0 = dws * ub(a, 0); acc1 = dws * ub(a, 1);
        acc2 = dws * ub(a, 2); acc3 = dws * ub(a, 3);
    } else {
        uint2 g = *(const uint2*)(srcb + (((unsigned)c << 9) + s8));
        acc0 = dw * b2f_lo(g.x); acc1 = dw * b2f_hi(g.x);
        acc2 = dw * b2f_lo(g.y); acc3 = dw * b2f_hi(g.y);
    }
    int e = offs[c], e1 = offs[c + 1];  // multiples of 4; pads have w=0
    for (; e < e1; e += 4) {
        int2 E[4];
#pragma unroll
        for (int u = 0; u < 4; ++u) E[u] = csr[e + u];
        if (U8) {
            unsigned a[4];
            float wv[4];
#pragma unroll
            for (int u = 0; u < 4; ++u) {
                wv[u] = __builtin_bit_cast(float, E[u].y) * qs[E[u].x];
                a[u] = *(const unsigned*)(srcu + (((unsigned)E[u].x << 7) + s4));
            }
#pragma unroll
            for (int u = 0; u < 4; ++u) {
                acc0 = fmaf(wv[u], ub(a[u], 0), acc0);
                acc1 = fmaf(wv[u], ub(a[u], 1), acc1);
                acc2 = fmaf(wv[u], ub(a[u], 2), acc2);
                acc3 = fmaf(wv[u], ub(a[u], 3), acc3);
            }
        } else {
            uint2 g[4];
#pragma unroll
            for (int u = 0; u < 4; ++u)
                g[u] = *(const uint2*)(srcb + (((unsigned)E[u].x << 9) + s8));
#pragma unroll
            for (int u = 0; u < 4; ++u) {
                float wv = __builtin_bit_cast(float, E[u].y);
                acc0 = fmaf(wv, b2f_lo(g[u].x), acc0);
                acc1 = fmaf(wv, b2f_hi(g[u].x), acc1);
                acc2 = fmaf(wv, b2f_lo(g[u].y), acc2);
                acc3 = fmaf(wv, b2f_hi(g[u].y), acc3);
            }
        }
    }
    uint2 outv;
    outv.x = (unsigned)f2b(0.5f * acc0) | ((unsigned)f2b(0.5f * acc1) << 16);
    outv.y = (unsigned)f2b(0.5f * acc2) | ((unsigned)f2b(0.5f * acc3) << 16);
    *(uint2*)((unsigned char*)abuf + (((unsigned)c << 9) + s8)) = outv;
}

// ---------------- layer GEMM (MFMA) -> bf16 packed outb + stats ----------------
__global__ __launch_bounds__(256) void k_gemm4(const unsigned short* __restrict__ A,
                                               const unsigned short* __restrict__ Bp,
                                               unsigned short* __restrict__ outb,
                                               float* __restrict__ stats) {
    __shared__ __attribute__((aligned(16))) unsigned short Bs[32768];
    int t = threadIdx.x;
#pragma unroll
    for (int it = 0; it < 16; ++it) {
        int o = it * 2048 + t * 8;
        *(bhalf8*)&Bs[o] = *(const bhalf8*)&Bp[o];
    }
    __syncthreads();

    int w = t >> 6, lane = t & 63;
    int q = lane >> 4, r = lane & 15;
    float ps1 = 0.f, ps2 = 0.f;

#pragma unroll 1
    for (int sub = 0; sub < 2; ++sub) {
        int m0 = blockIdx.x * 128 + sub * 64 + w * 16;
        int mA = m0 + r; if (mA > NNODES - 1) mA = NNODES - 1;
        const unsigned short* arow = A + (size_t)mA * 256;

        f32x4 acc[8];
#pragma unroll
        for (int i = 0; i < 8; ++i) acc[i] = (f32x4){0.f, 0.f, 0.f, 0.f};

        bhalf8 afr[8];
#pragma unroll
        for (int s = 0; s < 8; ++s)
            afr[s] = *(const bhalf8*)(arow + s * 32 + q * 8);
#pragma unroll
        for (int s = 0; s < 8; ++s) {
#pragma unroll
            for (int nt = 0; nt < 8; ++nt) {
                bhalf8 bfr = *(const bhalf8*)&Bs[((s * 8 + nt) << 9) + lane * 8];
                acc[nt] = __builtin_amdgcn_mfma_f32_16x16x32_bf16(afr[s], bfr, acc[nt], 0, 0, 0);
            }
        }
#pragma unroll
        for (int i = 0; i < 4; ++i) {
            int mm = m0 + q * 4 + i;
            if (mm < NNODES) {
                bhalf8 hv;
#pragma unroll
                for (int nt = 0; nt < 8; ++nt) {
                    float v = acc[nt][i];
                    ps1 += v; ps2 += v * v;
                    hv[nt] = (short)f2b(v);
                }
                *(bhalf8*)&outb[(size_t)mm * 128 + 8 * r] = hv;
            }
        }
    }
    __syncthreads();
    float* red = (float*)Bs;
    red[t] = ps1; red[256 + t] = ps2;
    __syncthreads();
    for (int o = 128; o > 0; o >>= 1) {
        if (t < o) { red[t] += red[t + o]; red[256 + t] += red[256 + t + o]; }
        __syncthreads();
    }
    if (t == 0) {
        atomicAdd(stats, red[0]);
        atomicAdd(stats + 1, red[256]);
    }
}

// ---------------- activation: per-row u8 quant of relu(LN(outb)), exact rowmax scale ----------------
__global__ __launch_bounds__(256) void k_actq(const unsigned short* __restrict__ outb,
                                              const float* __restrict__ stats,
                                              const float* __restrict__ nw,
                                              const float* __restrict__ nb,
                                              unsigned char* __restrict__ hact,
                                              float* __restrict__ qs) {
    __shared__ float skp[128], ckp[128];
    int t = threadIdx.x;
    const float M = (float)NNODES * 128.0f;
    float mean = stats[0] / M;
    float var = stats[1] / M - mean * mean;
    float inv = 1.0f / (sqrtf(fmaxf(var, 0.0f)) + 1e-5f);
    if (t < 128) {
        int d = invp(t);
        float sk = inv * nw[d];
        skp[t] = sk;
        ckp[t] = nb[d] - mean * sk;
    }
    __syncthreads();
    int row = blockIdx.x * 8 + (t >> 5);
    int s = t & 31;
    if (row >= NNODES) return;
    uint2 g = *(const uint2*)(outb + (size_t)row * 128 + s * 4);
    float h[4];
    h[0] = fmaxf(fmaf(b2f_lo(g.x), skp[4 * s + 0], ckp[4 * s + 0]), 0.0f);
    h[1] = fmaxf(fmaf(b2f_hi(g.x), skp[4 * s + 1], ckp[4 * s + 1]), 0.0f);
    h[2] = fmaxf(fmaf(b2f_lo(g.y), skp[4 * s + 2], ckp[4 * s + 2]), 0.0f);
    h[3] = fmaxf(fmaf(b2f_hi(g.y), skp[4 * s + 3], ckp[4 * s + 3]), 0.0f);
    float rmax = fmaxf(fmaxf(h[0], h[1]), fmaxf(h[2], h[3]));
#pragma unroll
    for (int o = 1; o < 32; o <<= 1) rmax = fmaxf(rmax, __shfl_xor(rmax, o));
    float rs = (rmax > 0.f) ? 255.0f / rmax : 0.0f;
    unsigned pk = 0;
#pragma unroll
    for (int k = 0; k < 4; ++k) {
        float a = fminf(h[k] * rs, 255.0f);
        pk |= __float2uint_rn(a) << (8 * k);
    }
    *(unsigned*)(hact + (size_t)row * 128 + s * 4) = pk;
    if (s == 0) qs[row] = (rmax > 0.f) ? rmax * (1.0f / 255.0f) : 0.0f;
}

// ---------------- lin2 (MFMA) with fused final LayerNorm+ReLU ----------------
__global__ __launch_bounds__(256) void k_lin2m(const unsigned short* __restrict__ outb,
                                               const float* __restrict__ stats,
                                               const float* __restrict__ nw,
                                               const float* __restrict__ nb,
                                               const float* __restrict__ W,
                                               const float* __restrict__ b,
                                               float* __restrict__ out) {
    __shared__ __attribute__((aligned(16))) unsigned short Bs[8192];
    __shared__ float lskp[128], lckp[128];
    int t = threadIdx.x;
    const float M = (float)NNODES * 128.0f;
    float mean = stats[0] / M;
    float var = stats[1] / M - mean * mean;
    float inv = 1.0f / (sqrtf(fmaxf(var, 0.0f)) + 1e-5f);
    for (int idx = t; idx < 8192; idx += 256) {
        int s = idx >> 11;
        int tt = (idx >> 9) & 3;
        int lane = (idx >> 3) & 63;
        int j = idx & 7;
        int kf = s * 32 + (lane >> 4) * 8 + j;
        int k = invp(kf);
        int n = tt * 16 + (lane & 15);
        Bs[idx] = f2b(W[k * 64 + n]);
    }
    if (t < 128) {
        int d = invp(t);
        float sk = inv * nw[d];
        lskp[t] = sk;
        lckp[t] = nb[d] - mean * sk;
    }
    __syncthreads();

    int w = t >> 6, lane = t & 63;
    int q = lane >> 4, r = lane & 15;
    int m0 = blockIdx.x * 64 + w * 16;
    int mA = m0 + r; if (mA > NNODES - 1) mA = NNODES - 1;
    const unsigned short* arow = outb + (size_t)mA * 128;

    f32x4 acc[4];
#pragma unroll
    for (int tt = 0; tt < 4; ++tt) {
        float bv = b[tt * 16 + r];
        acc[tt] = (f32x4){bv, bv, bv, bv};
    }
#pragma unroll
    for (int s = 0; s < 4; ++s) {
        bhalf8 raw = *(const bhalf8*)(arow + s * 32 + q * 8);
        bhalf8 af;
#pragma unroll
        for (int j = 0; j < 8; ++j) {
            int p = s * 32 + q * 8 + j;
            float v = b2f((unsigned short)raw[j]);
            v = fmaxf(fmaf(v, lskp[p], lckp[p]), 0.0f);
            af[j] = (short)f2b(v);
        }
#pragma unroll
        for (int tt = 0; tt < 4; ++tt) {
            bhalf8 bf = *(const bhalf8*)&Bs[((s * 4 + tt) << 9) + lane * 8];
            acc[tt] = __builtin_amdgcn_mfma_f32_16x16x32_bf16(af, bf, acc[tt], 0, 0, 0);
        }
    }
#pragma unroll
    for (int i = 0; i < 4; ++i) {
        int mm = m0 + q * 4 + i;
        if (mm < NNODES) {
#pragma unroll
            for (int tt = 0; tt < 4; ++tt)
                out[(size_t)mm * 64 + tt * 16 + r] = acc[tt][i];
        }
    }
}

// ---------------- launch ----------------

extern "C" void kernel_launch(void* const* d_in, const int* in_sizes, int n_in,
                              void* d_out, int out_size, void* d_ws, size_t ws_size,
                              hipStream_t stream) {
    const float* x      = (const float*)d_in[0];
    const int*   ei     = (const int*)d_in[1];
    const float* lin1_w = (const float*)d_in[2];
    const float* lin1_b = (const float*)d_in[3];
    const float* w1     = (const float*)d_in[4];
    const float* w2     = (const float*)d_in[5];
    const float* norm_w = (const float*)d_in[6];
    const float* norm_b = (const float*)d_in[7];
    const float* lin2_w = (const float*)d_in[8];
    const float* lin2_b = (const float*)d_in[9];
    float* out = (float*)d_out;

    const int* row = ei;
    const int* col = ei + NEDGES;

    char* p = (char*)d_ws;
    auto take = [&](size_t bytes) -> char* {
        char* r = p;
        p += (bytes + 255) & ~(size_t)255;
        return r;
    };
    unsigned short* abuf = (unsigned short*)take((size_t)NNODES * 256 * 2);  // [agg|h0] bf16 packed
    unsigned short* outb = (unsigned short*)take((size_t)NNODES * 128 * 2);  // layer out bf16 packed
    unsigned char*  hact = (unsigned char*)take((size_t)NNODES * 128);       // activated u8
    float*          qs   = (float*)take((size_t)NNODES * 4);                 // per-row dequant scale
    unsigned short* Wp   = (unsigned short*)take((size_t)NLAYERS * 32768 * 2);
    float* dinv    = (float*)take((size_t)NNODES * 4);
    // contiguous zero-init zone: counts | cursor | stats
    char* zzone    = take((size_t)NNODES * 4 * 2 + 256);
    int*   counts  = (int*)zzone;
    int*   cursor  = (int*)(zzone + (size_t)NNODES * 4);
    float* stats   = (float*)(zzone + (size_t)NNODES * 4 * 2);
    int*   offs    = (int*)take((size_t)(NNODES + 1) * 4);
    int*   part    = (int*)take((size_t)NSCANB * 4);
    int2*  csr     = (int2*)take((size_t)CSRMAX * 8);

    hipMemsetAsync(zzone, 0, (size_t)NNODES * 4 * 2 + 256, stream);
    hipMemsetAsync(csr, 0, (size_t)CSRMAX * 8, stream);  // pads = {row 0, w 0}

    k_count<<<(NEDGES + 255) / 256, 256, 0, stream>>>(col, counts);
    k_dinv_bsum<<<NSCANB, 256, 0, stream>>>(counts, dinv, part);
    k_pscan<<<1, 256, 0, stream>>>(part);
    k_offs<<<NSCANB, 256, 0, stream>>>(counts, part, offs);
    k_scatter<<<(NEDGES + 255) / 256, 256, 0, stream>>>(row, col, offs, cursor, dinv, csr);
    k_wcp2<<<(NLAYERS * 32768 + 255) / 256, 256, 0, stream>>>(w1, w2, Wp);
    k_lin1m<<<(NNODES + 63) / 64, 256, 0, stream>>>(x, lin1_w, lin1_b, abuf);

    for (int i = 0; i < NLAYERS; ++i) {
        if (i == 0) {
            k_spmm9<0><<<(NNODES * 32 + 255) / 256, 256, 0, stream>>>(
                nullptr, nullptr, (const unsigned char*)(abuf + 128), offs, csr, dinv, abuf);
        } else {
            k_spmm9<1><<<(NNODES * 32 + 255) / 256, 256, 0, stream>>>(
                hact, qs, nullptr, offs, csr, dinv, abuf);
        }
        k_gemm4<<<(NNODES + 127) / 128, 256, 0, stream>>>(abuf, Wp + (size_t)i * 32768,
                                                          outb, stats + 2 * i);
        if (i < NLAYERS - 1) {
            k_actq<<<(NNODES + 7) / 8, 256, 0, stream>>>(outb, stats + 2 * i,
                                                         norm_w + (size_t)i * 128,
                                                         norm_b + (size_t)i * 128,
                                                         hact, qs);
        }
    }
    k_lin2m<<<(NNODES + 63) / 64, 256, 0, stream>>>(outb, stats + 14,
                                                    norm_w + 7 * 128, norm_b + 7 * 128,
                                                    lin2_w, lin2_b, out);
}

// Round 14
// 549.526 us; speedup vs baseline: 1.8947x; 1.0711x over previous
//
#include <hip/hip_runtime.h>
#include <hip/hip_bf16.h>
#include <math.h>

#define NNODES 50000
#define NEDGES 500000
#define NLAYERS 8
#define NSCANB 196  // ceil(NNODES/256)
#define CSRMAX (NEDGES + 3 * NNODES)  // padded-to-4 worst case

typedef __attribute__((ext_vector_type(8))) short bhalf8;
typedef __attribute__((ext_vector_type(4))) float f32x4;

// K-dim permutation: packed pos p <-> natural dim d = 16*(p&7) + (p>>3).
static __device__ __forceinline__ int invp(int p) { return 16 * (p & 7) + (p >> 3); }

static __device__ __forceinline__ unsigned short f2b(float v) {
    unsigned u = __builtin_bit_cast(unsigned, v);
    u += 0x7fffu + ((u >> 16) & 1u);
    return (unsigned short)(u >> 16);
}
static __device__ __forceinline__ float b2f(unsigned short w) {
    return __builtin_bit_cast(float, (unsigned)w << 16);
}
static __device__ __forceinline__ float b2f_lo(unsigned w) {
    return __builtin_bit_cast(float, w << 16);
}
static __device__ __forceinline__ float b2f_hi(unsigned w) {
    return __builtin_bit_cast(float, w & 0xffff0000u);
}
static __device__ __forceinline__ float ub(unsigned a, int k) {
    return (float)((a >> (8 * k)) & 0xffu);  // folds to v_cvt_f32_ubyteN
}

// ---------------- graph preprocessing ----------------

__global__ void k_count(const int* __restrict__ col, int* __restrict__ counts) {
    int e = blockIdx.x * 256 + threadIdx.x;
    if (e < NEDGES) atomicAdd(&counts[col[e]], 1);
}

__global__ __launch_bounds__(256) void k_dinv_bsum(const int* __restrict__ counts,
                                                   float* __restrict__ dinv,
                                                   int* __restrict__ part) {
    __shared__ int ls[256];
    int t = threadIdx.x, i = blockIdx.x * 256 + t;
    int cnt = (i < NNODES) ? counts[i] : 0;
    if (i < NNODES) dinv[i] = rsqrtf((float)(cnt + 1));
    ls[t] = (i < NNODES) ? ((cnt + 3) & ~3) : 0;
    __syncthreads();
    for (int o = 128; o > 0; o >>= 1) {
        if (t < o) ls[t] += ls[t + o];
        __syncthreads();
    }
    if (t == 0) part[blockIdx.x] = ls[0];
}

__global__ __launch_bounds__(256) void k_pscan(int* __restrict__ part) {
    __shared__ int ls[256];
    int t = threadIdx.x;
    int v = (t < NSCANB) ? part[t] : 0;
    ls[t] = v;
    __syncthreads();
    for (int o = 1; o < 256; o <<= 1) {
        int x = (t >= o) ? ls[t - o] : 0;
        __syncthreads();
        ls[t] += x;
        __syncthreads();
    }
    if (t < NSCANB) part[t] = ls[t] - v;
}

__global__ __launch_bounds__(256) void k_offs(const int* __restrict__ counts,
                                              const int* __restrict__ part,
                                              int* __restrict__ offs) {
    __shared__ int ls[256];
    int t = threadIdx.x, i = blockIdx.x * 256 + t;
    int v = (i < NNODES) ? ((counts[i] + 3) & ~3) : 0;
    ls[t] = v;
    __syncthreads();
    for (int o = 1; o < 256; o <<= 1) {
        int x = (t >= o) ? ls[t - o] : 0;
        __syncthreads();
        ls[t] += x;
        __syncthreads();
    }
    int excl = part[blockIdx.x] + ls[t] - v;
    if (i < NNODES) offs[i] = excl;
    if (i == NNODES - 1) offs[NNODES] = excl + v;
}

// csr pre-memset to 0 -> pad entries are {row 0, w 0.0f}
__global__ void k_scatter(const int* __restrict__ row, const int* __restrict__ col,
                          const int* __restrict__ offs, int* __restrict__ cursor,
                          const float* __restrict__ dinv, int2* __restrict__ csr) {
    int e = blockIdx.x * 256 + threadIdx.x;
    if (e < NEDGES) {
        int c = col[e], r = row[e];
        int pos = offs[c] + atomicAdd(&cursor[c], 1);
        float w = dinv[r] * dinv[c];
        csr[pos] = make_int2(r, __builtin_bit_cast(int, w));
    }
}

// ---------------- folded + packed layer weights (K-permuted) ----------------
__global__ void k_wcp2(const float* __restrict__ w1, const float* __restrict__ w2,
                       unsigned short* __restrict__ Wp) {
    int idx = blockIdx.x * 256 + threadIdx.x;
    if (idx >= NLAYERS * 32768) return;
    int i = idx >> 15;
    int rem = idx & 32767;
    int s = rem >> 12;
    int t = (rem >> 9) & 7;
    int lane = (rem >> 3) & 63;
    int j = rem & 7;
    int kf = s * 32 + (lane >> 4) * 8 + j;
    int n = t * 16 + (lane & 15);
    float beta = logf(1.0f / (float)(i + 1) + 1.0f);
    float v;
    if (kf < 128) {
        int k = invp(kf);
        v = beta * w1[(i * 128 + k) * 128 + n] + ((k == n) ? (1.0f - beta) : 0.0f);
    } else {
        int k2 = invp(kf - 128);
        v = 0.5f * (beta * w2[(i * 128 + k2) * 128 + n] + ((k2 == n) ? (1.0f - beta) : 0.0f));
    }
    Wp[idx] = f2b(v);
}

// ---------------- lin1 (MFMA): h0 -> abuf[:,128:256) bf16 packed ----------------
__global__ __launch_bounds__(256) void k_lin1m(const float* __restrict__ x,
                                               const float* __restrict__ W,
                                               const float* __restrict__ b,
                                               unsigned short* __restrict__ abuf) {
    __shared__ __attribute__((aligned(16))) unsigned short Bs[8192];
    int t = threadIdx.x;
    for (int idx = t; idx < 8192; idx += 256) {
        int s = idx >> 12;
        int tt = (idx >> 9) & 7;
        int lane = (idx >> 3) & 63;
        int j = idx & 7;
        int k = s * 32 + (lane >> 4) * 8 + j;
        int n = tt * 16 + (lane & 15);
        Bs[idx] = f2b(W[k * 128 + n]);
    }
    __syncthreads();

    int w = t >> 6, lane = t & 63;
    int q = lane >> 4, r = lane & 15;
    int m0 = blockIdx.x * 64 + w * 16;
    int mA = m0 + r; if (mA > NNODES - 1) mA = NNODES - 1;
    const float* xrow = x + (size_t)mA * 64;

    f32x4 acc[8];
#pragma unroll
    for (int tt = 0; tt < 8; ++tt) {
        float bv = b[tt * 16 + r];
        acc[tt] = (f32x4){bv, bv, bv, bv};
    }
#pragma unroll
    for (int s = 0; s < 2; ++s) {
        float xv[8];
        *(float4*)&xv[0] = *(const float4*)(xrow + s * 32 + q * 8);
        *(float4*)&xv[4] = *(const float4*)(xrow + s * 32 + q * 8 + 4);
        bhalf8 ah, al;
#pragma unroll
        for (int j = 0; j < 8; ++j) {
            unsigned short hb = f2b(xv[j]);
            ah[j] = (short)hb;
            al[j] = (short)f2b(xv[j] - b2f(hb));
        }
#pragma unroll
        for (int tt = 0; tt < 8; ++tt) {
            bhalf8 bf = *(const bhalf8*)&Bs[((s * 8 + tt) << 9) + lane * 8];
            acc[tt] = __builtin_amdgcn_mfma_f32_16x16x32_bf16(ah, bf, acc[tt], 0, 0, 0);
            acc[tt] = __builtin_amdgcn_mfma_f32_16x16x32_bf16(al, bf, acc[tt], 0, 0, 0);
        }
    }
#pragma unroll
    for (int i = 0; i < 4; ++i) {
        int mm = m0 + q * 4 + i;
        if (mm < NNODES) {
            bhalf8 hv;
#pragma unroll
            for (int tt = 0; tt < 8; ++tt) hv[tt] = (short)f2b(acc[tt][i]);
            *(bhalf8*)&abuf[(size_t)mm * 256 + 128 + 8 * r] = hv;
        }
    }
}

// ---------------- SpMM: padded CSR, 32-bit byte-offset gathers ----------------
template <int U8>
__global__ __launch_bounds__(256) void k_spmm9(const unsigned char* __restrict__ srcu,
                                               const float* __restrict__ qs,
                                               const unsigned char* __restrict__ srcb,
                                               const int* __restrict__ offs,
                                               const int2* __restrict__ csr,
                                               const float* __restrict__ dinv,
                                               unsigned short* __restrict__ abuf) {
    int gt = blockIdx.x * 256 + threadIdx.x;
    int c = gt >> 5;          // node (2 per wave)
    unsigned s = threadIdx.x & 31;  // packed dims [4s, 4s+4)
    if (c >= NNODES) return;
    unsigned s4 = s * 4, s8 = s * 8;
    float di = dinv[c];
    float dw = di * di;
    float acc0, acc1, acc2, acc3;
    if (U8) {
        unsigned a = *(const unsigned*)(srcu + (((unsigned)c << 7) + s4));
        float dws = dw * qs[c];
        acc0 = dws * ub(a, 0); acc1 = dws * ub(a, 1);
        acc2 = dws * ub(a, 2); acc3 = dws * ub(a, 3);
    } else {
        uint2 g = *(const uint2*)(srcb + (((unsigned)c << 9) + s8));
        acc0 = dw * b2f_lo(g.x); acc1 = dw * b2f_hi(g.x);
        acc2 = dw * b2f_lo(g.y); acc3 = dw * b2f_hi(g.y);
    }
    int e = offs[c], e1 = offs[c + 1];  // multiples of 4; pads have w=0
    for (; e < e1; e += 4) {
        int2 E[4];
#pragma unroll
        for (int u = 0; u < 4; ++u) E[u] = csr[e + u];
        if (U8) {
            unsigned a[4];
            float wv[4];
#pragma unroll
            for (int u = 0; u < 4; ++u) {
                wv[u] = __builtin_bit_cast(float, E[u].y) * qs[E[u].x];
                a[u] = *(const unsigned*)(srcu + (((unsigned)E[u].x << 7) + s4));
            }
#pragma unroll
            for (int u = 0; u < 4; ++u) {
                acc0 = fmaf(wv[u], ub(a[u], 0), acc0);
                acc1 = fmaf(wv[u], ub(a[u], 1), acc1);
                acc2 = fmaf(wv[u], ub(a[u], 2), acc2);
                acc3 = fmaf(wv[u], ub(a[u], 3), acc3);
            }
        } else {
            uint2 g[4];
#pragma unroll
            for (int u = 0; u < 4; ++u)
                g[u] = *(const uint2*)(srcb + (((unsigned)E[u].x << 9) + s8));
#pragma unroll
            for (int u = 0; u < 4; ++u) {
                float wv = __builtin_bit_cast(float, E[u].y);
                acc0 = fmaf(wv, b2f_lo(g[u].x), acc0);
                acc1 = fmaf(wv, b2f_hi(g[u].x), acc1);
                acc2 = fmaf(wv, b2f_lo(g[u].y), acc2);
                acc3 = fmaf(wv, b2f_hi(g[u].y), acc3);
            }
        }
    }
    uint2 outv;
    outv.x = (unsigned)f2b(0.5f * acc0) | ((unsigned)f2b(0.5f * acc1) << 16);
    outv.y = (unsigned)f2b(0.5f * acc2) | ((unsigned)f2b(0.5f * acc3) << 16);
    *(uint2*)((unsigned char*)abuf + (((unsigned)c << 9) + s8)) = outv;
}

// ---------------- layer GEMM (MFMA): M=256 x N=64 tiles, 32 KB B-LDS ----------------
// grid = 196*2 blocks: mt = bx>>1, nh = bx&1 (N-half). 5 blocks/CU (LDS) vs 2 before.
__global__ __launch_bounds__(256) void k_gemm5(const unsigned short* __restrict__ A,
                                               const unsigned short* __restrict__ Bp,
                                               unsigned short* __restrict__ outb,
                                               float* __restrict__ stats) {
    __shared__ __attribute__((aligned(16))) unsigned short Bs[16384];  // 32 KB
    int t = threadIdx.x;
    int mt = blockIdx.x >> 1, nh = blockIdx.x & 1;
    // load this N-half's B fragments: local g = s*4+ntl; global nt = ntl + 4*nh
#pragma unroll
    for (int it = 0; it < 8; ++it) {
        int o = it * 2048 + t * 8;
        int g = o >> 9;
        int s = g >> 2, ntl = g & 3;
        int src = (((s * 8) + ntl + 4 * nh) << 9) + (o & 511);
        *(bhalf8*)&Bs[o] = *(const bhalf8*)&Bp[src];
    }
    __syncthreads();

    int w = t >> 6, lane = t & 63;
    int q = lane >> 4, r = lane & 15;
    float ps1 = 0.f, ps2 = 0.f;

#pragma unroll 1
    for (int sub = 0; sub < 4; ++sub) {
        int m0 = mt * 256 + sub * 64 + w * 16;
        int mA = m0 + r; if (mA > NNODES - 1) mA = NNODES - 1;
        const unsigned short* arow = A + (size_t)mA * 256;

        f32x4 acc[4];
#pragma unroll
        for (int i = 0; i < 4; ++i) acc[i] = (f32x4){0.f, 0.f, 0.f, 0.f};

        bhalf8 afr[8];
#pragma unroll
        for (int s = 0; s < 8; ++s)
            afr[s] = *(const bhalf8*)(arow + s * 32 + q * 8);
#pragma unroll
        for (int s = 0; s < 8; ++s) {
#pragma unroll
            for (int ntl = 0; ntl < 4; ++ntl) {
                bhalf8 bfr = *(const bhalf8*)&Bs[((s * 4 + ntl) << 9) + lane * 8];
                acc[ntl] = __builtin_amdgcn_mfma_f32_16x16x32_bf16(afr[s], bfr, acc[ntl], 0, 0, 0);
            }
        }
#pragma unroll
        for (int i = 0; i < 4; ++i) {
            int mm = m0 + q * 4 + i;
            if (mm < NNODES) {
                unsigned lo = 0, hi = 0;
#pragma unroll
                for (int ntl = 0; ntl < 4; ++ntl) {
                    float v = acc[ntl][i];
                    ps1 += v; ps2 += v * v;
                    unsigned bits = (unsigned)f2b(v);
                    if (ntl < 2) lo |= bits << (16 * ntl);
                    else         hi |= bits << (16 * (ntl - 2));
                }
                // packed pos p = 8*r + nt, nt = ntl + 4*nh -> 4 contiguous shorts
                *(uint2*)&outb[(size_t)mm * 128 + 8 * r + 4 * nh] = make_uint2(lo, hi);
            }
        }
    }
    __syncthreads();
    float* red = (float*)Bs;
    red[t] = ps1; red[256 + t] = ps2;
    __syncthreads();
    for (int o = 128; o > 0; o >>= 1) {
        if (t < o) { red[t] += red[t + o]; red[256 + t] += red[256 + t + o]; }
        __syncthreads();
    }
    if (t == 0) {
        atomicAdd(stats, red[0]);
        atomicAdd(stats + 1, red[256]);
    }
}

// ---------------- activation: per-row u8 quant of relu(LN(outb)), exact rowmax scale ----------------
__global__ __launch_bounds__(256) void k_actq(const unsigned short* __restrict__ outb,
                                              const float* __restrict__ stats,
                                              const float* __restrict__ nw,
                                              const float* __restrict__ nb,
                                              unsigned char* __restrict__ hact,
                                              float* __restrict__ qs) {
    __shared__ float skp[128], ckp[128];
    int t = threadIdx.x;
    const float M = (float)NNODES * 128.0f;
    float mean = stats[0] / M;
    float var = stats[1] / M - mean * mean;
    float inv = 1.0f / (sqrtf(fmaxf(var, 0.0f)) + 1e-5f);
    if (t < 128) {
        int d = invp(t);
        float sk = inv * nw[d];
        skp[t] = sk;
        ckp[t] = nb[d] - mean * sk;
    }
    __syncthreads();
    int row = blockIdx.x * 8 + (t >> 5);
    int s = t & 31;
    if (row >= NNODES) return;
    uint2 g = *(const uint2*)(outb + (size_t)row * 128 + s * 4);
    float h[4];
    h[0] = fmaxf(fmaf(b2f_lo(g.x), skp[4 * s + 0], ckp[4 * s + 0]), 0.0f);
    h[1] = fmaxf(fmaf(b2f_hi(g.x), skp[4 * s + 1], ckp[4 * s + 1]), 0.0f);
    h[2] = fmaxf(fmaf(b2f_lo(g.y), skp[4 * s + 2], ckp[4 * s + 2]), 0.0f);
    h[3] = fmaxf(fmaf(b2f_hi(g.y), skp[4 * s + 3], ckp[4 * s + 3]), 0.0f);
    float rmax = fmaxf(fmaxf(h[0], h[1]), fmaxf(h[2], h[3]));
#pragma unroll
    for (int o = 1; o < 32; o <<= 1) rmax = fmaxf(rmax, __shfl_xor(rmax, o));
    float rs = (rmax > 0.f) ? 255.0f / rmax : 0.0f;
    unsigned pk = 0;
#pragma unroll
    for (int k = 0; k < 4; ++k) {
        float a = fminf(h[k] * rs, 255.0f);
        pk |= __float2uint_rn(a) << (8 * k);
    }
    *(unsigned*)(hact + (size_t)row * 128 + s * 4) = pk;
    if (s == 0) qs[row] = (rmax > 0.f) ? rmax * (1.0f / 255.0f) : 0.0f;
}

// ---------------- lin2 (MFMA) with fused final LayerNorm+ReLU ----------------
__global__ __launch_bounds__(256) void k_lin2m(const unsigned short* __restrict__ outb,
                                               const float* __restrict__ stats,
                                               const float* __restrict__ nw,
                                               const float* __restrict__ nb,
                                               const float* __restrict__ W,
                                               const float* __restrict__ b,
                                               float* __restrict__ out) {
    __shared__ __attribute__((aligned(16))) unsigned short Bs[8192];
    __shared__ float lskp[128], lckp[128];
    int t = threadIdx.x;
    const float M = (float)NNODES * 128.0f;
    float mean = stats[0] / M;
    float var = stats[1] / M - mean * mean;
    float inv = 1.0f / (sqrtf(fmaxf(var, 0.0f)) + 1e-5f);
    for (int idx = t; idx < 8192; idx += 256) {
        int s = idx >> 11;
        int tt = (idx >> 9) & 3;
        int lane = (idx >> 3) & 63;
        int j = idx & 7;
        int kf = s * 32 + (lane >> 4) * 8 + j;
        int k = invp(kf);
        int n = tt * 16 + (lane & 15);
        Bs[idx] = f2b(W[k * 64 + n]);
    }
    if (t < 128) {
        int d = invp(t);
        float sk = inv * nw[d];
        lskp[t] = sk;
        lckp[t] = nb[d] - mean * sk;
    }
    __syncthreads();

    int w = t >> 6, lane = t & 63;
    int q = lane >> 4, r = lane & 15;
    int m0 = blockIdx.x * 64 + w * 16;
    int mA = m0 + r; if (mA > NNODES - 1) mA = NNODES - 1;
    const unsigned short* arow = outb + (size_t)mA * 128;

    f32x4 acc[4];
#pragma unroll
    for (int tt = 0; tt < 4; ++tt) {
        float bv = b[tt * 16 + r];
        acc[tt] = (f32x4){bv, bv, bv, bv};
    }
#pragma unroll
    for (int s = 0; s < 4; ++s) {
        bhalf8 raw = *(const bhalf8*)(arow + s * 32 + q * 8);
        bhalf8 af;
#pragma unroll
        for (int j = 0; j < 8; ++j) {
            int p = s * 32 + q * 8 + j;
            float v = b2f((unsigned short)raw[j]);
            v = fmaxf(fmaf(v, lskp[p], lckp[p]), 0.0f);
            af[j] = (short)f2b(v);
        }
#pragma unroll
        for (int tt = 0; tt < 4; ++tt) {
            bhalf8 bf = *(const bhalf8*)&Bs[((s * 4 + tt) << 9) + lane * 8];
            acc[tt] = __builtin_amdgcn_mfma_f32_16x16x32_bf16(af, bf, acc[tt], 0, 0, 0);
        }
    }
#pragma unroll
    for (int i = 0; i < 4; ++i) {
        int mm = m0 + q * 4 + i;
        if (mm < NNODES) {
#pragma unroll
            for (int tt = 0; tt < 4; ++tt)
                out[(size_t)mm * 64 + tt * 16 + r] = acc[tt][i];
        }
    }
}

// ---------------- launch ----------------

extern "C" void kernel_launch(void* const* d_in, const int* in_sizes, int n_in,
                              void* d_out, int out_size, void* d_ws, size_t ws_size,
                              hipStream_t stream) {
    const float* x      = (const float*)d_in[0];
    const int*   ei     = (const int*)d_in[1];
    const float* lin1_w = (const float*)d_in[2];
    const float* lin1_b = (const float*)d_in[3];
    const float* w1     = (const float*)d_in[4];
    const float* w2     = (const float*)d_in[5];
    const float* norm_w = (const float*)d_in[6];
    const float* norm_b = (const float*)d_in[7];
    const float* lin2_w = (const float*)d_in[8];
    const float* lin2_b = (const float*)d_in[9];
    float* out = (float*)d_out;

    const int* row = ei;
    const int* col = ei + NEDGES;

    char* p = (char*)d_ws;
    auto take = [&](size_t bytes) -> char* {
        char* r = p;
        p += (bytes + 255) & ~(size_t)255;
        return r;
    };
    unsigned short* abuf = (unsigned short*)take((size_t)NNODES * 256 * 2);  // [agg|h0] bf16 packed
    unsigned short* outb = (unsigned short*)take((size_t)NNODES * 128 * 2);  // layer out bf16 packed
    unsigned char*  hact = (unsigned char*)take((size_t)NNODES * 128);       // activated u8
    float*          qs   = (float*)take((size_t)NNODES * 4);                 // per-row dequant scale
    unsigned short* Wp   = (unsigned short*)take((size_t)NLAYERS * 32768 * 2);
    float* dinv    = (float*)take((size_t)NNODES * 4);
    // contiguous zero-init zone: counts | cursor | stats
    char* zzone    = take((size_t)NNODES * 4 * 2 + 256);
    int*   counts  = (int*)zzone;
    int*   cursor  = (int*)(zzone + (size_t)NNODES * 4);
    float* stats   = (float*)(zzone + (size_t)NNODES * 4 * 2);
    int*   offs    = (int*)take((size_t)(NNODES + 1) * 4);
    int*   part    = (int*)take((size_t)NSCANB * 4);
    int2*  csr     = (int2*)take((size_t)CSRMAX * 8);

    hipMemsetAsync(zzone, 0, (size_t)NNODES * 4 * 2 + 256, stream);
    hipMemsetAsync(csr, 0, (size_t)CSRMAX * 8, stream);  // pads = {row 0, w 0}

    k_count<<<(NEDGES + 255) / 256, 256, 0, stream>>>(col, counts);
    k_dinv_bsum<<<NSCANB, 256, 0, stream>>>(counts, dinv, part);
    k_pscan<<<1, 256, 0, stream>>>(part);
    k_offs<<<NSCANB, 256, 0, stream>>>(counts, part, offs);
    k_scatter<<<(NEDGES + 255) / 256, 256, 0, stream>>>(row, col, offs, cursor, dinv, csr);
    k_wcp2<<<(NLAYERS * 32768 + 255) / 256, 256, 0, stream>>>(w1, w2, Wp);
    k_lin1m<<<(NNODES + 63) / 64, 256, 0, stream>>>(x, lin1_w, lin1_b, abuf);

    const int NGB = ((NNODES + 255) / 256) * 2;  // 196 m-tiles x 2 n-halves = 392
    for (int i = 0; i < NLAYERS; ++i) {
        if (i == 0) {
            k_spmm9<0><<<(NNODES * 32 + 255) / 256, 256, 0, stream>>>(
                nullptr, nullptr, (const unsigned char*)(abuf + 128), offs, csr, dinv, abuf);
        } else {
            k_spmm9<1><<<(NNODES * 32 + 255) / 256, 256, 0, stream>>>(
                hact, qs, nullptr, offs, csr, dinv, abuf);
        }
        k_gemm5<<<NGB, 256, 0, stream>>>(abuf, Wp + (size_t)i * 32768,
                                         outb, stats + 2 * i);
        if (i < NLAYERS - 1) {
            k_actq<<<(NNODES + 7) / 8, 256, 0, stream>>>(outb, stats + 2 * i,
                                                         norm_w + (size_t)i * 128,
                                                         norm_b + (size_t)i * 128,
                                                         hact, qs);
        }
    }
    k_lin2m<<<(NNODES + 63) / 64, 256, 0, stream>>>(outb, stats + 14,
                                                    norm_w + 7 * 128, norm_b + 7 * 128,
                                                    lin2_w, lin2_b, out);
}